// Round 1
// baseline (678.983 us; speedup 1.0000x reference)
//
#include <hip/hip_runtime.h>

#define NN 50000
#define NE 640000

// ---------------- degree histogram ----------------
__global__ __launch_bounds__(256) void k_deg(const int* __restrict__ src,
                                             const int* __restrict__ dst,
                                             int* __restrict__ out_cnt,
                                             int* __restrict__ in_cnt) {
  int e = blockIdx.x * 256 + threadIdx.x;
  if (e < NE) {
    atomicAdd(&out_cnt[src[e]], 1);
    atomicAdd(&in_cnt[dst[e]], 1);
  }
}

// ---------------- norms ----------------
__global__ __launch_bounds__(256) void k_norm(const int* __restrict__ out_cnt,
                                              const int* __restrict__ in_cnt,
                                              float* __restrict__ nsrc,
                                              float* __restrict__ ndst) {
  int n = blockIdx.x * 256 + threadIdx.x;
  if (n < NN) {
    nsrc[n] = 1.0f / sqrtf((float)max(out_cnt[n], 1));
    ndst[n] = 1.0f / sqrtf((float)max(in_cnt[n], 1));
  }
}

// ---------------- exclusive scan of in-degree (single block, wave-scan based) ----------------
__global__ __launch_bounds__(1024) void k_scan(const int* __restrict__ cnt,
                                               int* __restrict__ row_start) {
  __shared__ int wsum[16];
  __shared__ int ctot;
  int tid = threadIdx.x;
  int lane = tid & 63, wid = tid >> 6;
  int carry = 0;
  for (int base = 0; base < NN; base += 4096) {
    int i0 = base + tid * 4;
    int v[4];
#pragma unroll
    for (int t = 0; t < 4; ++t) v[t] = (i0 + t < NN) ? cnt[i0 + t] : 0;
    int s = v[0] + v[1] + v[2] + v[3];
    // inclusive wave scan of s
    int sc = s;
#pragma unroll
    for (int off = 1; off < 64; off <<= 1) {
      int t = __shfl_up(sc, off);
      if (lane >= off) sc += t;
    }
    if (lane == 63) wsum[wid] = sc;
    __syncthreads();
    if (wid == 0) {
      int ws = (lane < 16) ? wsum[lane] : 0;
      int wsc = ws;
#pragma unroll
      for (int off = 1; off < 16; off <<= 1) {
        int t = __shfl_up(wsc, off);
        if (lane >= off) wsc += t;
      }
      if (lane == 15) ctot = wsc;
      if (lane < 16) wsum[lane] = wsc - ws;  // exclusive wave offsets
    }
    __syncthreads();
    int excl = carry + wsum[wid] + (sc - s);
#pragma unroll
    for (int t = 0; t < 4; ++t) {
      if (i0 + t < NN) row_start[i0 + t] = excl;
      excl += v[t];
    }
    carry += ctot;
    __syncthreads();  // protect wsum/ctot before next chunk overwrites
  }
}

// ---------------- CSR fill ----------------
__global__ __launch_bounds__(256) void k_fill(const int* __restrict__ src,
                                              const int* __restrict__ dst,
                                              const int* __restrict__ row_start,
                                              int* __restrict__ cursor,
                                              int* __restrict__ col) {
  int e = blockIdx.x * 256 + threadIdx.x;
  if (e < NE) {
    int d = dst[e];
    int pos = atomicAdd(&cursor[d], 1);
    col[row_start[d] + pos] = src[e];
  }
}

// ---------------- embedding: h = nf @ W_emb + b_emb ----------------
__global__ __launch_bounds__(256) void k_embed(const float* __restrict__ nf,
                                               const float* __restrict__ W,
                                               const float* __restrict__ b,
                                               float* __restrict__ h) {
  int idx = blockIdx.x * 256 + threadIdx.x;  // over NN*128
  int n = idx >> 7, j = idx & 127;
  const float* f = nf + n * 4;
  float acc = b[j];
  acc += f[0] * W[j] + f[1] * W[128 + j] + f[2] * W[256 + j] + f[3] * W[384 + j];
  h[idx] = acc;
}

// ---------------- SpMM: out[n] = ndst[n] * sum_{s in CSR(n)} nsrc[s]*h[s] ----------------
__global__ __launch_bounds__(256) void k_spmm(const float* __restrict__ h,
                                              float* __restrict__ outp,
                                              const int* __restrict__ col,
                                              const int* __restrict__ row_start,
                                              const int* __restrict__ in_cnt,
                                              const float* __restrict__ nsrc,
                                              const float* __restrict__ ndst) {
  int node = blockIdx.x * 4 + (threadIdx.x >> 6);
  int lane = threadIdx.x & 63;
  int start = row_start[node];
  int cnt = in_cnt[node];
  float ax = 0.f, ay = 0.f;
  const float2* h2 = (const float2*)h;
  for (int i = 0; i < cnt; ++i) {
    int s = col[start + i];
    float ns = nsrc[s];
    float2 v = h2[(size_t)s * 64 + lane];
    ax = fmaf(ns, v.x, ax);
    ay = fmaf(ns, v.y, ay);
  }
  float nd = ndst[node];
  float2 r;
  r.x = ax * nd;
  r.y = ay * nd;
  ((float2*)outp)[(size_t)node * 64 + lane] = r;
}

// ---------------- in-place GEMM: buf = relu(buf @ W + bias), [M,128]x[128,128] ----------------
__global__ __launch_bounds__(256) void k_gemm_relu(float* __restrict__ buf,
                                                   const float* __restrict__ W,
                                                   const float* __restrict__ bias,
                                                   int M) {
  __shared__ float As[64 * 132];  // 64 rows x 128 cols, pad 4
  __shared__ float Ws[32 * 132];  // 32 k-rows x 128 cols, pad 4
  int tid = threadIdx.x;
  int brow = blockIdx.x * 64;
  // stage full A tile (in-place safe: stores happen after full staging)
#pragma unroll
  for (int i = 0; i < 8; ++i) {
    int idx = i * 256 + tid;      // 2048 float4
    int r = idx >> 5, c4 = idx & 31;
    int gr = brow + r;
    if (gr >= M) gr = M - 1;      // clamp; clamped rows masked on store
    float4 v = *(const float4*)(buf + (size_t)gr * 128 + c4 * 4);
    *(float4*)&As[r * 132 + c4 * 4] = v;
  }
  int tx = tid & 15, ty = tid >> 4;  // 16 col-groups x 16 row-groups
  float acc[4][8];
#pragma unroll
  for (int i = 0; i < 4; ++i)
#pragma unroll
    for (int j = 0; j < 8; ++j) acc[i][j] = 0.f;

  for (int kc = 0; kc < 4; ++kc) {
    __syncthreads();  // As staged (first iter) / Ws consumers done (later iters)
#pragma unroll
    for (int i = 0; i < 4; ++i) {
      int idx = i * 256 + tid;    // 1024 float4
      int r = idx >> 5, c4 = idx & 31;
      *(float4*)&Ws[r * 132 + c4 * 4] =
          *(const float4*)(W + (size_t)(kc * 32 + r) * 128 + c4 * 4);
    }
    __syncthreads();
#pragma unroll
    for (int k4 = 0; k4 < 8; ++k4) {
      int k = k4 * 4;
      float4 a[4];
#pragma unroll
      for (int i = 0; i < 4; ++i)
        a[i] = *(const float4*)&As[(ty * 4 + i) * 132 + kc * 32 + k];
      float w[4][8];
#pragma unroll
      for (int t = 0; t < 4; ++t) {
        float4 lo = *(const float4*)&Ws[(k + t) * 132 + tx * 8];
        float4 hi = *(const float4*)&Ws[(k + t) * 132 + tx * 8 + 4];
        w[t][0] = lo.x; w[t][1] = lo.y; w[t][2] = lo.z; w[t][3] = lo.w;
        w[t][4] = hi.x; w[t][5] = hi.y; w[t][6] = hi.z; w[t][7] = hi.w;
      }
#pragma unroll
      for (int i = 0; i < 4; ++i) {
        float a0 = a[i].x, a1 = a[i].y, a2 = a[i].z, a3 = a[i].w;
#pragma unroll
        for (int j = 0; j < 8; ++j)
          acc[i][j] += a0 * w[0][j] + a1 * w[1][j] + a2 * w[2][j] + a3 * w[3][j];
      }
    }
  }
  float bv[8];
#pragma unroll
  for (int j = 0; j < 8; ++j) bv[j] = bias[tx * 8 + j];
#pragma unroll
  for (int i = 0; i < 4; ++i) {
    int gr = brow + ty * 4 + i;
    if (gr < M) {
      float4 lo, hi;
      lo.x = fmaxf(acc[i][0] + bv[0], 0.f);
      lo.y = fmaxf(acc[i][1] + bv[1], 0.f);
      lo.z = fmaxf(acc[i][2] + bv[2], 0.f);
      lo.w = fmaxf(acc[i][3] + bv[3], 0.f);
      hi.x = fmaxf(acc[i][4] + bv[4], 0.f);
      hi.y = fmaxf(acc[i][5] + bv[5], 0.f);
      hi.z = fmaxf(acc[i][6] + bv[6], 0.f);
      hi.w = fmaxf(acc[i][7] + bv[7], 0.f);
      *(float4*)(buf + (size_t)gr * 128 + tx * 8) = lo;
      *(float4*)(buf + (size_t)gr * 128 + tx * 8 + 4) = hi;
    }
  }
}

// ---------------- final: out[n] = h[n,:] . W_o2 + b_o2 ----------------
__global__ __launch_bounds__(256) void k_final(const float* __restrict__ h,
                                               const float* __restrict__ W_o2,
                                               const float* __restrict__ b_o2,
                                               float* __restrict__ out) {
  int node = blockIdx.x * 4 + (threadIdx.x >> 6);
  int lane = threadIdx.x & 63;
  float2 v = ((const float2*)(h + (size_t)node * 128))[lane];
  float2 w = ((const float2*)W_o2)[lane];
  float d = v.x * w.x + v.y * w.y;
#pragma unroll
  for (int m = 32; m >= 1; m >>= 1) d += __shfl_xor(d, m);
  if (lane == 0) out[node] = d + b_o2[0];
}

extern "C" void kernel_launch(void* const* d_in, const int* in_sizes, int n_in,
                              void* d_out, int out_size, void* d_ws, size_t ws_size,
                              hipStream_t stream) {
  const float* node_feats = (const float*)d_in[0];
  const int* src = (const int*)d_in[1];
  const int* dst = (const int*)d_in[2];
  const float* W_emb = (const float*)d_in[3];
  const float* b_emb = (const float*)d_in[4];
  const float* W_g = (const float*)d_in[5];
  const float* b_g = (const float*)d_in[6];
  const float* W_o1 = (const float*)d_in[7];
  const float* b_o1 = (const float*)d_in[8];
  const float* W_o2 = (const float*)d_in[9];
  const float* b_o2 = (const float*)d_in[10];
  float* out = (float*)d_out;

  char* ws = (char*)d_ws;
  int* out_cnt   = (int*)(ws + 0);        // 200000 B (pad 200192)
  int* in_cnt    = (int*)(ws + 200192);
  int* cursor    = (int*)(ws + 400384);
  int* row_start = (int*)(ws + 600576);
  float* nsrc    = (float*)(ws + 800768);
  float* ndst    = (float*)(ws + 1000960);
  int* col       = (int*)(ws + 1201152);  // 2,560,000 B
  float* hA      = (float*)(ws + 3761152);   // 25.6 MB
  float* hB      = (float*)(ws + 29361152);  // 25.6 MB

  // zero the atomic counters (out_cnt, in_cnt, cursor are contiguous)
  hipMemsetAsync(d_ws, 0, 600576, stream);

  k_deg<<<(NE + 255) / 256, 256, 0, stream>>>(src, dst, out_cnt, in_cnt);
  k_norm<<<(NN + 255) / 256, 256, 0, stream>>>(out_cnt, in_cnt, nsrc, ndst);
  k_scan<<<1, 1024, 0, stream>>>(in_cnt, row_start);
  k_fill<<<(NE + 255) / 256, 256, 0, stream>>>(src, dst, row_start, cursor, col);
  k_embed<<<(NN * 128) / 256, 256, 0, stream>>>(node_feats, W_emb, b_emb, hA);

  float* cur = hA;
  float* tmp = hB;
  for (int l = 0; l < 3; ++l) {
    k_spmm<<<NN / 4, 256, 0, stream>>>(cur, tmp, col, row_start, in_cnt, nsrc, ndst);
    k_gemm_relu<<<(NN + 63) / 64, 256, 0, stream>>>(tmp, W_g + (size_t)l * 128 * 128,
                                                    b_g + (size_t)l * 128, NN);
    float* t = cur; cur = tmp; tmp = t;
  }
  k_gemm_relu<<<(NN + 63) / 64, 256, 0, stream>>>(cur, W_o1, b_o1, NN);
  k_final<<<NN / 4, 256, 0, stream>>>(cur, W_o2, b_o2, out);
}

// Round 2
// 596.660 us; speedup vs baseline: 1.1380x; 1.1380x over previous
//
#include <hip/hip_runtime.h>

#define NN 50000
#define NE 640000

// ---------------- degree histogram ----------------
__global__ __launch_bounds__(256) void k_deg(const int* __restrict__ src,
                                             const int* __restrict__ dst,
                                             int* __restrict__ out_cnt,
                                             int* __restrict__ in_cnt) {
  int e = blockIdx.x * 256 + threadIdx.x;
  if (e < NE) {
    atomicAdd(&out_cnt[src[e]], 1);
    atomicAdd(&in_cnt[dst[e]], 1);
  }
}

// ---------------- norms ----------------
__global__ __launch_bounds__(256) void k_norm(const int* __restrict__ out_cnt,
                                              const int* __restrict__ in_cnt,
                                              float* __restrict__ nsrc,
                                              float* __restrict__ ndst) {
  int n = blockIdx.x * 256 + threadIdx.x;
  if (n < NN) {
    nsrc[n] = 1.0f / sqrtf((float)max(out_cnt[n], 1));
    ndst[n] = 1.0f / sqrtf((float)max(in_cnt[n], 1));
  }
}

// ---------------- exclusive scan of in-degree (single block) ----------------
__global__ __launch_bounds__(1024) void k_scan(const int* __restrict__ cnt,
                                               int* __restrict__ row_start) {
  __shared__ int wsum[16];
  __shared__ int ctot;
  int tid = threadIdx.x;
  int lane = tid & 63, wid = tid >> 6;
  int carry = 0;
  for (int base = 0; base < NN; base += 4096) {
    int i0 = base + tid * 4;
    int v[4];
#pragma unroll
    for (int t = 0; t < 4; ++t) v[t] = (i0 + t < NN) ? cnt[i0 + t] : 0;
    int s = v[0] + v[1] + v[2] + v[3];
    int sc = s;
#pragma unroll
    for (int off = 1; off < 64; off <<= 1) {
      int t = __shfl_up(sc, off);
      if (lane >= off) sc += t;
    }
    if (lane == 63) wsum[wid] = sc;
    __syncthreads();
    if (wid == 0) {
      int ws = (lane < 16) ? wsum[lane] : 0;
      int wsc = ws;
#pragma unroll
      for (int off = 1; off < 16; off <<= 1) {
        int t = __shfl_up(wsc, off);
        if (lane >= off) wsc += t;
      }
      if (lane == 15) ctot = wsc;
      if (lane < 16) wsum[lane] = wsc - ws;
    }
    __syncthreads();
    int excl = carry + wsum[wid] + (sc - s);
#pragma unroll
    for (int t = 0; t < 4; ++t) {
      if (i0 + t < NN) row_start[i0 + t] = excl;
      excl += v[t];
    }
    carry += ctot;
    __syncthreads();
  }
}

// ---------------- CSR fill ----------------
__global__ __launch_bounds__(256) void k_fill(const int* __restrict__ src,
                                              const int* __restrict__ dst,
                                              const int* __restrict__ row_start,
                                              int* __restrict__ cursor,
                                              int* __restrict__ col) {
  int e = blockIdx.x * 256 + threadIdx.x;
  if (e < NE) {
    int d = dst[e];
    int pos = atomicAdd(&cursor[d], 1);
    col[row_start[d] + pos] = src[e];
  }
}

// ---------------- embedding: xs = (nf @ W_emb + b_emb) * nsrc ----------------
__global__ __launch_bounds__(256) void k_embed(const float* __restrict__ nf,
                                               const float* __restrict__ W,
                                               const float* __restrict__ b,
                                               const float* __restrict__ nsrc,
                                               float* __restrict__ xs) {
  int idx = blockIdx.x * 256 + threadIdx.x;  // over NN*128
  int n = idx >> 7, j = idx & 127;
  const float* f = nf + n * 4;
  float acc = b[j];
  acc += f[0] * W[j] + f[1] * W[128 + j] + f[2] * W[256 + j] + f[3] * W[384 + j];
  xs[idx] = acc * nsrc[n];
}

// ---------------- SpMM: out[n] = ndst[n] * sum_{s in CSR(n)} xs[s] ----------------
// one wave per node; two edges in flight via half-waves; float4 per lane; ×2 unroll
__global__ __launch_bounds__(256) void k_spmm(const float* __restrict__ xs,
                                              float* __restrict__ outp,
                                              const int* __restrict__ col,
                                              const int* __restrict__ row_start,
                                              const int* __restrict__ in_cnt,
                                              const float* __restrict__ ndst) {
  int node = blockIdx.x * 4 + (threadIdx.x >> 6);
  int lane = threadIdx.x & 63;
  int half = lane >> 5;
  int qlane = lane & 31;
  int start = row_start[node];
  int cnt = in_cnt[node];
  float4 acc = make_float4(0.f, 0.f, 0.f, 0.f);
  const float4* X4 = (const float4*)xs;  // row stride = 32 float4
  for (int base = 0; base < cnt; base += 64) {
    int m = min(cnt - base, 64);
    int ccol = (lane < m) ? col[start + base + lane] : 0;
    int jj = 0;
    for (; jj + 3 < m; jj += 4) {
      int s0 = __shfl(ccol, jj + half);
      int s1 = __shfl(ccol, jj + 2 + half);
      float4 v0 = X4[(size_t)s0 * 32 + qlane];
      float4 v1 = X4[(size_t)s1 * 32 + qlane];
      acc.x += v0.x; acc.y += v0.y; acc.z += v0.z; acc.w += v0.w;
      acc.x += v1.x; acc.y += v1.y; acc.z += v1.z; acc.w += v1.w;
    }
    for (; jj < m; jj += 2) {
      int j = jj + half;
      int s = __shfl(ccol, (j < m) ? j : 0);
      if (j < m) {
        float4 v = X4[(size_t)s * 32 + qlane];
        acc.x += v.x; acc.y += v.y; acc.z += v.z; acc.w += v.w;
      }
    }
  }
  acc.x += __shfl_down(acc.x, 32);
  acc.y += __shfl_down(acc.y, 32);
  acc.z += __shfl_down(acc.z, 32);
  acc.w += __shfl_down(acc.w, 32);
  if (half == 0) {
    float nd = ndst[node];
    acc.x *= nd; acc.y *= nd; acc.z *= nd; acc.w *= nd;
    ((float4*)outp)[(size_t)node * 32 + qlane] = acc;
  }
}

// ---------------- GEMM: dst = relu(buf @ W + bias) [* nsrc]  ----------------
// If xsout != null: write relu_out * nsrc into xsout (buf untouched).
// Else: write relu_out in-place into buf.
__global__ __launch_bounds__(256) void k_gemm_relu(float* __restrict__ buf,
                                                   const float* __restrict__ W,
                                                   const float* __restrict__ bias,
                                                   float* __restrict__ xsout,
                                                   const float* __restrict__ nsrc,
                                                   int M) {
  __shared__ float As[64 * 132];  // 64 rows x 128 cols, pad 4
  __shared__ float Ws[16 * 260];  // [colgroup 16][k 32][8], stride 260 (2-way banks)
  int tid = threadIdx.x;
  int brow = blockIdx.x * 64;
#pragma unroll
  for (int i = 0; i < 8; ++i) {
    int idx = i * 256 + tid;  // 2048 float4
    int r = idx >> 5, c4 = idx & 31;
    int gr = brow + r;
    if (gr >= M) gr = M - 1;
    float4 v = *(const float4*)(buf + (size_t)gr * 128 + c4 * 4);
    *(float4*)&As[r * 132 + c4 * 4] = v;
  }
  int tx = tid & 15, ty = tid >> 4;
  float acc[4][8];
#pragma unroll
  for (int i = 0; i < 4; ++i)
#pragma unroll
    for (int j = 0; j < 8; ++j) acc[i][j] = 0.f;

  for (int kc = 0; kc < 4; ++kc) {
    __syncthreads();
#pragma unroll
    for (int i = 0; i < 4; ++i) {
      int idx = i * 256 + tid;  // 1024 float4
      int r = idx >> 5, c4 = idx & 31;
      float4 v = *(const float4*)(W + (size_t)(kc * 32 + r) * 128 + c4 * 4);
      int cg = c4 >> 1, sub = (c4 & 1) * 4;
      *(float4*)&Ws[cg * 260 + r * 8 + sub] = v;
    }
    __syncthreads();
#pragma unroll
    for (int k4 = 0; k4 < 8; ++k4) {
      int k = k4 * 4;
      float4 a[4];
#pragma unroll
      for (int i = 0; i < 4; ++i)
        a[i] = *(const float4*)&As[(ty * 4 + i) * 132 + kc * 32 + k];
      float w[4][8];
#pragma unroll
      for (int t = 0; t < 4; ++t) {
        float4 lo = *(const float4*)&Ws[tx * 260 + (k + t) * 8];
        float4 hi = *(const float4*)&Ws[tx * 260 + (k + t) * 8 + 4];
        w[t][0] = lo.x; w[t][1] = lo.y; w[t][2] = lo.z; w[t][3] = lo.w;
        w[t][4] = hi.x; w[t][5] = hi.y; w[t][6] = hi.z; w[t][7] = hi.w;
      }
#pragma unroll
      for (int i = 0; i < 4; ++i) {
        float a0 = a[i].x, a1 = a[i].y, a2 = a[i].z, a3 = a[i].w;
#pragma unroll
        for (int j = 0; j < 8; ++j)
          acc[i][j] += a0 * w[0][j] + a1 * w[1][j] + a2 * w[2][j] + a3 * w[3][j];
      }
    }
  }
  float bv[8];
#pragma unroll
  for (int j = 0; j < 8; ++j) bv[j] = bias[tx * 8 + j];
  float* outbase = xsout ? xsout : buf;
#pragma unroll
  for (int i = 0; i < 4; ++i) {
    int gr = brow + ty * 4 + i;
    if (gr < M) {
      float sc = xsout ? nsrc[gr] : 1.0f;
      float4 lo, hi;
      lo.x = fmaxf(acc[i][0] + bv[0], 0.f) * sc;
      lo.y = fmaxf(acc[i][1] + bv[1], 0.f) * sc;
      lo.z = fmaxf(acc[i][2] + bv[2], 0.f) * sc;
      lo.w = fmaxf(acc[i][3] + bv[3], 0.f) * sc;
      hi.x = fmaxf(acc[i][4] + bv[4], 0.f) * sc;
      hi.y = fmaxf(acc[i][5] + bv[5], 0.f) * sc;
      hi.z = fmaxf(acc[i][6] + bv[6], 0.f) * sc;
      hi.w = fmaxf(acc[i][7] + bv[7], 0.f) * sc;
      *(float4*)(outbase + (size_t)gr * 128 + tx * 8) = lo;
      *(float4*)(outbase + (size_t)gr * 128 + tx * 8 + 4) = hi;
    }
  }
}

// ---------------- final: out[n] = h[n,:] . W_o2 + b_o2 ----------------
__global__ __launch_bounds__(256) void k_final(const float* __restrict__ h,
                                               const float* __restrict__ W_o2,
                                               const float* __restrict__ b_o2,
                                               float* __restrict__ out) {
  int node = blockIdx.x * 4 + (threadIdx.x >> 6);
  int lane = threadIdx.x & 63;
  float2 v = ((const float2*)(h + (size_t)node * 128))[lane];
  float2 w = ((const float2*)W_o2)[lane];
  float d = v.x * w.x + v.y * w.y;
#pragma unroll
  for (int m = 32; m >= 1; m >>= 1) d += __shfl_xor(d, m);
  if (lane == 0) out[node] = d + b_o2[0];
}

extern "C" void kernel_launch(void* const* d_in, const int* in_sizes, int n_in,
                              void* d_out, int out_size, void* d_ws, size_t ws_size,
                              hipStream_t stream) {
  const float* node_feats = (const float*)d_in[0];
  const int* src = (const int*)d_in[1];
  const int* dst = (const int*)d_in[2];
  const float* W_emb = (const float*)d_in[3];
  const float* b_emb = (const float*)d_in[4];
  const float* W_g = (const float*)d_in[5];
  const float* b_g = (const float*)d_in[6];
  const float* W_o1 = (const float*)d_in[7];
  const float* b_o1 = (const float*)d_in[8];
  const float* W_o2 = (const float*)d_in[9];
  const float* b_o2 = (const float*)d_in[10];
  float* out = (float*)d_out;

  char* ws = (char*)d_ws;
  int* out_cnt   = (int*)(ws + 0);
  int* in_cnt    = (int*)(ws + 200192);
  int* cursor    = (int*)(ws + 400384);
  int* row_start = (int*)(ws + 600576);
  float* nsrc    = (float*)(ws + 800768);
  float* ndst    = (float*)(ws + 1000960);
  int* col       = (int*)(ws + 1201152);     // 2,560,000 B
  float* A       = (float*)(ws + 3761152);   // 25.6 MB: spmm out / h (in-place gemm)
  float* X       = (float*)(ws + 29361152);  // 25.6 MB: xs = h * nsrc

  hipMemsetAsync(d_ws, 0, 600576, stream);

  k_deg<<<(NE + 255) / 256, 256, 0, stream>>>(src, dst, out_cnt, in_cnt);
  k_norm<<<(NN + 255) / 256, 256, 0, stream>>>(out_cnt, in_cnt, nsrc, ndst);
  k_scan<<<1, 1024, 0, stream>>>(in_cnt, row_start);
  k_fill<<<(NE + 255) / 256, 256, 0, stream>>>(src, dst, row_start, cursor, col);
  k_embed<<<(NN * 128) / 256, 256, 0, stream>>>(node_feats, W_emb, b_emb, nsrc, X);

  for (int l = 0; l < 3; ++l) {
    k_spmm<<<NN / 4, 256, 0, stream>>>(X, A, col, row_start, in_cnt, ndst);
    float* xsout = (l < 2) ? X : nullptr;
    k_gemm_relu<<<(NN + 63) / 64, 256, 0, stream>>>(A, W_g + (size_t)l * 128 * 128,
                                                    b_g + (size_t)l * 128, xsout, nsrc, NN);
  }
  k_gemm_relu<<<(NN + 63) / 64, 256, 0, stream>>>(A, W_o1, b_o1, nullptr, nsrc, NN);
  k_final<<<NN / 4, 256, 0, stream>>>(A, W_o2, b_o2, out);
}

// Round 3
// 419.453 us; speedup vs baseline: 1.6187x; 1.4225x over previous
//
#include <hip/hip_runtime.h>

#define NN 50000
#define NE 640000
#define SCAN_B 196  // ceil(NN/256)

typedef short bf16x8 __attribute__((ext_vector_type(8)));
typedef float f32x4 __attribute__((ext_vector_type(4)));

__device__ __forceinline__ unsigned short f2bf(float f) {
  unsigned int u = __float_as_uint(f);
  unsigned int r = (u + 0x7FFFu + ((u >> 16) & 1u)) >> 16;
  return (unsigned short)r;
}
__device__ __forceinline__ float bf2f(unsigned short h) {
  return __uint_as_float(((unsigned int)h) << 16);
}

typedef const __attribute__((address_space(1))) void* gptr_t;
typedef __attribute__((address_space(3))) void* lptr_t;
__device__ __forceinline__ void gload16(const void* g, void* l) {
  __builtin_amdgcn_global_load_lds((gptr_t)g, (lptr_t)l, 16, 0, 0);
}

// ---------------- degree histogram ----------------
__global__ __launch_bounds__(256) void k_deg(const int* __restrict__ src,
                                             const int* __restrict__ dst,
                                             int* __restrict__ out_cnt,
                                             int* __restrict__ in_cnt) {
  int e = blockIdx.x * 256 + threadIdx.x;
  if (e < NE) {
    atomicAdd(&out_cnt[src[e]], 1);
    atomicAdd(&in_cnt[dst[e]], 1);
  }
}

// ---------------- norms ----------------
__global__ __launch_bounds__(256) void k_norm(const int* __restrict__ out_cnt,
                                              const int* __restrict__ in_cnt,
                                              float* __restrict__ nsrc,
                                              float* __restrict__ ndst) {
  int n = blockIdx.x * 256 + threadIdx.x;
  if (n < NN) {
    nsrc[n] = 1.0f / sqrtf((float)max(out_cnt[n], 1));
    ndst[n] = 1.0f / sqrtf((float)max(in_cnt[n], 1));
  }
}

// ---------------- parallel scan (3 kernels) ----------------
__global__ __launch_bounds__(256) void k_scan1(const int* __restrict__ cnt,
                                               int* __restrict__ bsum) {
  int t = threadIdx.x, i = blockIdx.x * 256 + t;
  int v = (i < NN) ? cnt[i] : 0;
#pragma unroll
  for (int o = 32; o >= 1; o >>= 1) v += __shfl_down(v, o);
  __shared__ int ws4[4];
  if ((t & 63) == 0) ws4[t >> 6] = v;
  __syncthreads();
  if (t == 0) bsum[blockIdx.x] = ws4[0] + ws4[1] + ws4[2] + ws4[3];
}

__global__ __launch_bounds__(256) void k_scan2(const int* __restrict__ bsum,
                                               int* __restrict__ boff) {
  int t = threadIdx.x, lane = t & 63, w = t >> 6;
  int v = (t < SCAN_B) ? bsum[t] : 0;
  int sc = v;
#pragma unroll
  for (int o = 1; o < 64; o <<= 1) {
    int x = __shfl_up(sc, o);
    if (lane >= o) sc += x;
  }
  __shared__ int wtot[4];
  if (lane == 63) wtot[w] = sc;
  __syncthreads();
  int base = 0;
  for (int i = 0; i < w; ++i) base += wtot[i];
  if (t < SCAN_B) boff[t] = base + sc - v;
}

__global__ __launch_bounds__(256) void k_scan3(const int* __restrict__ cnt,
                                               const int* __restrict__ boff,
                                               int* __restrict__ row_start) {
  int b = blockIdx.x, t = threadIdx.x, lane = t & 63, w = t >> 6;
  int i = b * 256 + t;
  int v = (i < NN) ? cnt[i] : 0;
  int sc = v;
#pragma unroll
  for (int o = 1; o < 64; o <<= 1) {
    int x = __shfl_up(sc, o);
    if (lane >= o) sc += x;
  }
  __shared__ int wtot[4];
  if (lane == 63) wtot[w] = sc;
  __syncthreads();
  int base = boff[b];
  for (int j = 0; j < w; ++j) base += wtot[j];
  if (i < NN) row_start[i] = base + sc - v;
}

// ---------------- CSR fill ----------------
__global__ __launch_bounds__(256) void k_fill(const int* __restrict__ src,
                                              const int* __restrict__ dst,
                                              const int* __restrict__ row_start,
                                              int* __restrict__ cursor,
                                              int* __restrict__ col) {
  int e = blockIdx.x * 256 + threadIdx.x;
  if (e < NE) {
    int d = dst[e];
    int pos = atomicAdd(&cursor[d], 1);
    col[row_start[d] + pos] = src[e];
  }
}

// ---------------- weight prep: Wt[mat] = split(W^T) as bf16 hi/lo [n][k] ----------------
__global__ __launch_bounds__(256) void k_prep(const float* __restrict__ Wg,
                                              const float* __restrict__ Wo1,
                                              unsigned short* __restrict__ wt) {
  int idx = blockIdx.x * 256 + threadIdx.x;  // 4 * 16384
  int mat = idx >> 14, rem = idx & 16383;
  int k = rem >> 7, n = rem & 127;
  const float* Wsrc = (mat < 3) ? (Wg + mat * 16384) : Wo1;
  float v = Wsrc[k * 128 + n];
  unsigned short hi = f2bf(v);
  float lo = v - bf2f(hi);
  unsigned short* base = wt + mat * 32768;
  base[n * 128 + k] = hi;
  base[16384 + n * 128 + k] = f2bf(lo);
}

// ---------------- embedding: xs = (nf @ W_emb + b_emb) * nsrc ----------------
__global__ __launch_bounds__(256) void k_embed(const float* __restrict__ nf,
                                               const float* __restrict__ W,
                                               const float* __restrict__ b,
                                               const float* __restrict__ nsrc,
                                               float* __restrict__ xs) {
  int idx = blockIdx.x * 256 + threadIdx.x;
  int n = idx >> 7, j = idx & 127;
  const float* f = nf + n * 4;
  float acc = b[j];
  acc += f[0] * W[j] + f[1] * W[128 + j] + f[2] * W[256 + j] + f[3] * W[384 + j];
  xs[idx] = acc * nsrc[n];
}

// ---------------- SpMM: a[n] = ndst[n]*sum xs[src]; write bf16 hi/lo split ----------------
__global__ __launch_bounds__(256) void k_spmm(const float* __restrict__ xs,
                                              unsigned short* __restrict__ ahi,
                                              unsigned short* __restrict__ alo,
                                              const int* __restrict__ col,
                                              const int* __restrict__ row_start,
                                              const int* __restrict__ in_cnt,
                                              const float* __restrict__ ndst) {
  int node = blockIdx.x * 4 + (threadIdx.x >> 6);
  int lane = threadIdx.x & 63;
  int half = lane >> 5;
  int qlane = lane & 31;
  int start = row_start[node];
  int cnt = in_cnt[node];
  float4 acc = make_float4(0.f, 0.f, 0.f, 0.f);
  const float4* X4 = (const float4*)xs;
  for (int base = 0; base < cnt; base += 64) {
    int m = min(cnt - base, 64);
    int ccol = (lane < m) ? col[start + base + lane] : 0;
    int jj = 0;
    for (; jj + 7 < m; jj += 8) {
      int s0 = __shfl(ccol, jj + half);
      int s1 = __shfl(ccol, jj + 2 + half);
      int s2 = __shfl(ccol, jj + 4 + half);
      int s3 = __shfl(ccol, jj + 6 + half);
      float4 v0 = X4[(size_t)s0 * 32 + qlane];
      float4 v1 = X4[(size_t)s1 * 32 + qlane];
      float4 v2 = X4[(size_t)s2 * 32 + qlane];
      float4 v3 = X4[(size_t)s3 * 32 + qlane];
      acc.x += v0.x + v1.x + v2.x + v3.x;
      acc.y += v0.y + v1.y + v2.y + v3.y;
      acc.z += v0.z + v1.z + v2.z + v3.z;
      acc.w += v0.w + v1.w + v2.w + v3.w;
    }
    for (; jj < m; jj += 2) {
      int j = jj + half;
      int s = __shfl(ccol, (j < m) ? j : 0);
      if (j < m) {
        float4 v = X4[(size_t)s * 32 + qlane];
        acc.x += v.x; acc.y += v.y; acc.z += v.z; acc.w += v.w;
      }
    }
  }
  acc.x += __shfl_down(acc.x, 32);
  acc.y += __shfl_down(acc.y, 32);
  acc.z += __shfl_down(acc.z, 32);
  acc.w += __shfl_down(acc.w, 32);
  if (half == 0) {
    float nd = ndst[node];
    float v0 = acc.x * nd, v1 = acc.y * nd, v2 = acc.z * nd, v3 = acc.w * nd;
    ushort4 h, l;
    h.x = f2bf(v0); l.x = f2bf(v0 - bf2f(h.x));
    h.y = f2bf(v1); l.y = f2bf(v1 - bf2f(h.y));
    h.z = f2bf(v2); l.z = f2bf(v2 - bf2f(h.z));
    h.w = f2bf(v3); l.w = f2bf(v3 - bf2f(h.w));
    *(ushort4*)(ahi + (size_t)node * 128 + qlane * 4) = h;
    *(ushort4*)(alo + (size_t)node * 128 + qlane * 4) = l;
  }
}

// ---------------- MFMA GEMM (bf16x3 split): out = relu(A @ Wt^T + bias) ----------------
// modes: 0 = write fp32 * nsrc (xs), 1 = write bf16 hi/lo, 2 = write plain fp32
__global__ __launch_bounds__(256) void k_gemm_mfma(
    const unsigned short* __restrict__ Ahi, const unsigned short* __restrict__ Alo,
    const unsigned short* __restrict__ Wth, const unsigned short* __restrict__ Wtl,
    const float* __restrict__ bias, float* __restrict__ outf,
    unsigned short* __restrict__ outhi, unsigned short* __restrict__ outlo,
    const float* __restrict__ nsrc, int M, int mode) {
  __shared__ unsigned short sm[2 * 64 * 128];  // Ah (16KB) then Al (16KB)
  int tid = threadIdx.x;
  int lane = tid & 63, w = tid >> 6;
  int tile0 = blockIdx.x * 64;

  // stage A hi/lo via global_load_lds: linear LDS dest, pre-XOR-swizzled global src
  {
    int slot = lane & 15;
#pragma unroll
    for (int j = 0; j < 4; ++j) {
      int ldsoff = w * 4096 + j * 1024;       // byte offset within half
      int row = (ldsoff >> 8) + (lane >> 4);  // 0..63
      int grow = tile0 + row;
      if (grow > M - 1) grow = M - 1;
      size_t gsrc = (size_t)grow * 256 + (size_t)(((slot ^ (row & 7)) << 4));
      gload16((const char*)Ahi + gsrc, (char*)sm + ldsoff);
      gload16((const char*)Alo + gsrc, (char*)sm + 16384 + ldsoff);
    }
  }

  // B fragments in registers (Wt layout [n][k] bf16)
  bf16x8 bh[2][4], bl[2][4];
  {
    int koff = (lane >> 4) * 8;
#pragma unroll
    for (int cf = 0; cf < 2; ++cf) {
      int n = w * 32 + cf * 16 + (lane & 15);
      const unsigned short* ph = Wth + (size_t)n * 128 + koff;
      const unsigned short* pl = Wtl + (size_t)n * 128 + koff;
#pragma unroll
      for (int kc = 0; kc < 4; ++kc) {
        bh[cf][kc] = *(const bf16x8*)(ph + kc * 32);
        bl[cf][kc] = *(const bf16x8*)(pl + kc * 32);
      }
    }
  }

  f32x4 acc[4][2] = {};
  __syncthreads();  // drains vmcnt -> staged A complete

  int r15 = lane & 15, kq = lane >> 4;
  for (int kc = 0; kc < 4; ++kc) {
    bf16x8 ah[4], al[4];
#pragma unroll
    for (int m = 0; m < 4; ++m) {
      int row = m * 16 + r15;
      int boff = row * 256 + ((((kc * 4 + kq) ^ (row & 7))) << 4);
      ah[m] = *(const bf16x8*)((const char*)sm + boff);
      al[m] = *(const bf16x8*)((const char*)sm + 16384 + boff);
    }
#pragma unroll
    for (int m = 0; m < 4; ++m)
#pragma unroll
      for (int cf = 0; cf < 2; ++cf) {
        acc[m][cf] = __builtin_amdgcn_mfma_f32_16x16x32_bf16(ah[m], bh[cf][kc], acc[m][cf], 0, 0, 0);
        acc[m][cf] = __builtin_amdgcn_mfma_f32_16x16x32_bf16(ah[m], bl[cf][kc], acc[m][cf], 0, 0, 0);
        acc[m][cf] = __builtin_amdgcn_mfma_f32_16x16x32_bf16(al[m], bh[cf][kc], acc[m][cf], 0, 0, 0);
      }
  }

  // epilogue: D[row=(kq*4+i)+m*16][col=r15+cf*16+w*32]
#pragma unroll
  for (int cf = 0; cf < 2; ++cf) {
    int colg = w * 32 + cf * 16 + r15;
    float bv = bias[colg];
#pragma unroll
    for (int m = 0; m < 4; ++m) {
#pragma unroll
      for (int i = 0; i < 4; ++i) {
        int gr = tile0 + m * 16 + kq * 4 + i;
        if (gr < M) {
          float v = fmaxf(acc[m][cf][i] + bv, 0.f);
          if (mode == 0) {
            outf[(size_t)gr * 128 + colg] = v * nsrc[gr];
          } else if (mode == 2) {
            outf[(size_t)gr * 128 + colg] = v;
          } else {
            unsigned short h = f2bf(v);
            outhi[(size_t)gr * 128 + colg] = h;
            outlo[(size_t)gr * 128 + colg] = f2bf(v - bf2f(h));
          }
        }
      }
    }
  }
}

// ---------------- final: out[n] = h[n,:] . W_o2 + b_o2 ----------------
__global__ __launch_bounds__(256) void k_final(const float* __restrict__ h,
                                               const float* __restrict__ W_o2,
                                               const float* __restrict__ b_o2,
                                               float* __restrict__ out) {
  int node = blockIdx.x * 4 + (threadIdx.x >> 6);
  int lane = threadIdx.x & 63;
  float2 v = ((const float2*)(h + (size_t)node * 128))[lane];
  float2 w = ((const float2*)W_o2)[lane];
  float d = v.x * w.x + v.y * w.y;
#pragma unroll
  for (int m = 32; m >= 1; m >>= 1) d += __shfl_xor(d, m);
  if (lane == 0) out[node] = d + b_o2[0];
}

extern "C" void kernel_launch(void* const* d_in, const int* in_sizes, int n_in,
                              void* d_out, int out_size, void* d_ws, size_t ws_size,
                              hipStream_t stream) {
  const float* node_feats = (const float*)d_in[0];
  const int* src = (const int*)d_in[1];
  const int* dst = (const int*)d_in[2];
  const float* W_emb = (const float*)d_in[3];
  const float* b_emb = (const float*)d_in[4];
  const float* W_g = (const float*)d_in[5];
  const float* b_g = (const float*)d_in[6];
  const float* W_o1 = (const float*)d_in[7];
  const float* b_o1 = (const float*)d_in[8];
  const float* W_o2 = (const float*)d_in[9];
  const float* b_o2 = (const float*)d_in[10];
  float* out = (float*)d_out;

  char* ws = (char*)d_ws;
  int* out_cnt   = (int*)(ws + 0);
  int* in_cnt    = (int*)(ws + 200704);
  int* cursor    = (int*)(ws + 401408);
  int* row_start = (int*)(ws + 602112);
  float* nsrc    = (float*)(ws + 802816);
  float* ndst    = (float*)(ws + 1003520);
  int* bsum      = (int*)(ws + 1204224);
  int* boff      = (int*)(ws + 1205248);
  int* col       = (int*)(ws + 1206272);           // 2,560,000 B
  unsigned short* wt = (unsigned short*)(ws + 3766272);  // 262,144 B
  float* X       = (float*)(ws + 4028416);          // 25.6 MB (xs fp32; later Bhi/Blo)
  unsigned short* Xu = (unsigned short*)(ws + 4028416);
  unsigned short* Ahi = (unsigned short*)(ws + 29628416);
  unsigned short* Alo = (unsigned short*)(ws + 42428416);
  float* Hf      = (float*)(ws + 29628416);         // o1 output (fp32, aliases A pair)

  hipMemsetAsync(d_ws, 0, 602112, stream);  // out_cnt, in_cnt, cursor

  k_deg<<<(NE + 255) / 256, 256, 0, stream>>>(src, dst, out_cnt, in_cnt);
  k_norm<<<(NN + 255) / 256, 256, 0, stream>>>(out_cnt, in_cnt, nsrc, ndst);
  k_scan1<<<SCAN_B, 256, 0, stream>>>(in_cnt, bsum);
  k_scan2<<<1, 256, 0, stream>>>(bsum, boff);
  k_scan3<<<SCAN_B, 256, 0, stream>>>(in_cnt, boff, row_start);
  k_fill<<<(NE + 255) / 256, 256, 0, stream>>>(src, dst, row_start, cursor, col);
  k_prep<<<256, 256, 0, stream>>>(W_g, W_o1, wt);
  k_embed<<<(NN * 128) / 256, 256, 0, stream>>>(node_feats, W_emb, b_emb, nsrc, X);

  int gemm_grid = (NN + 63) / 64;
  for (int l = 0; l < 3; ++l) {
    k_spmm<<<NN / 4, 256, 0, stream>>>(X, Ahi, Alo, col, row_start, in_cnt, ndst);
    unsigned short* wth = wt + l * 32768;
    unsigned short* wtl = wth + 16384;
    if (l < 2) {
      k_gemm_mfma<<<gemm_grid, 256, 0, stream>>>(Ahi, Alo, wth, wtl, b_g + l * 128,
                                                 X, nullptr, nullptr, nsrc, NN, 0);
    } else {
      k_gemm_mfma<<<gemm_grid, 256, 0, stream>>>(Ahi, Alo, wth, wtl, b_g + l * 128,
                                                 nullptr, Xu, Xu + 6400000, nsrc, NN, 1);
    }
  }
  // o1: reads hi/lo from X region, writes fp32 h into A region
  k_gemm_mfma<<<gemm_grid, 256, 0, stream>>>(Xu, Xu + 6400000, wt + 3 * 32768,
                                             wt + 3 * 32768 + 16384, b_o1,
                                             Hf, nullptr, nullptr, nsrc, NN, 2);
  k_final<<<NN / 4, 256, 0, stream>>>(Hf, W_o2, b_o2, out);
}

// Round 4
// 385.279 us; speedup vs baseline: 1.7623x; 1.0887x over previous
//
#include <hip/hip_runtime.h>

#define NN 50000
#define NE 640000
#define SCAN_B 196  // ceil(NN/256)

typedef short bf16x8 __attribute__((ext_vector_type(8)));
typedef float f32x4 __attribute__((ext_vector_type(4)));

__device__ __forceinline__ unsigned short f2bf(float f) {
  unsigned int u = __float_as_uint(f);
  unsigned int r = (u + 0x7FFFu + ((u >> 16) & 1u)) >> 16;
  return (unsigned short)r;
}
__device__ __forceinline__ float bf2f(unsigned short h) {
  return __uint_as_float(((unsigned int)h) << 16);
}

typedef const __attribute__((address_space(1))) void* gptr_t;
typedef __attribute__((address_space(3))) void* lptr_t;
__device__ __forceinline__ void gload16(const void* g, void* l) {
  __builtin_amdgcn_global_load_lds((gptr_t)g, (lptr_t)l, 16, 0, 0);
}

// ---------------- degree histogram + per-edge rank ----------------
__global__ __launch_bounds__(256) void k_deg(const int* __restrict__ src,
                                             const int* __restrict__ dst,
                                             int* __restrict__ out_cnt,
                                             int* __restrict__ in_cnt,
                                             int* __restrict__ rank) {
  int e = blockIdx.x * 256 + threadIdx.x;
  if (e < NE) {
    atomicAdd(&out_cnt[src[e]], 1);
    rank[e] = atomicAdd(&in_cnt[dst[e]], 1);
  }
}

// ---------------- scan stage 1 (fused norms) ----------------
__global__ __launch_bounds__(256) void k_scan1(const int* __restrict__ out_cnt,
                                               const int* __restrict__ in_cnt,
                                               float* __restrict__ nsrc,
                                               float* __restrict__ ndst,
                                               int* __restrict__ bsum) {
  int t = threadIdx.x, i = blockIdx.x * 256 + t;
  int v = 0;
  if (i < NN) {
    v = in_cnt[i];
    nsrc[i] = 1.0f / sqrtf((float)max(out_cnt[i], 1));
    ndst[i] = 1.0f / sqrtf((float)max(v, 1));
  }
  int s = v;
#pragma unroll
  for (int o = 32; o >= 1; o >>= 1) s += __shfl_down(s, o);
  __shared__ int ws4[4];
  if ((t & 63) == 0) ws4[t >> 6] = s;
  __syncthreads();
  if (t == 0) bsum[blockIdx.x] = ws4[0] + ws4[1] + ws4[2] + ws4[3];
}

__global__ __launch_bounds__(256) void k_scan2(const int* __restrict__ bsum,
                                               int* __restrict__ boff) {
  int t = threadIdx.x, lane = t & 63, w = t >> 6;
  int v = (t < SCAN_B) ? bsum[t] : 0;
  int sc = v;
#pragma unroll
  for (int o = 1; o < 64; o <<= 1) {
    int x = __shfl_up(sc, o);
    if (lane >= o) sc += x;
  }
  __shared__ int wtot[4];
  if (lane == 63) wtot[w] = sc;
  __syncthreads();
  int base = 0;
  for (int i = 0; i < w; ++i) base += wtot[i];
  if (t < SCAN_B) boff[t] = base + sc - v;
}

__global__ __launch_bounds__(256) void k_scan3(const int* __restrict__ cnt,
                                               const int* __restrict__ boff,
                                               int* __restrict__ row_start) {
  int b = blockIdx.x, t = threadIdx.x, lane = t & 63, w = t >> 6;
  int i = b * 256 + t;
  int v = (i < NN) ? cnt[i] : 0;
  int sc = v;
#pragma unroll
  for (int o = 1; o < 64; o <<= 1) {
    int x = __shfl_up(sc, o);
    if (lane >= o) sc += x;
  }
  __shared__ int wtot[4];
  if (lane == 63) wtot[w] = sc;
  __syncthreads();
  int base = boff[b];
  for (int j = 0; j < w; ++j) base += wtot[j];
  if (i < NN) row_start[i] = base + sc - v;
}

// ---------------- CSR fill (atomic-free via rank) ----------------
__global__ __launch_bounds__(256) void k_fill(const int* __restrict__ src,
                                              const int* __restrict__ dst,
                                              const int* __restrict__ row_start,
                                              const int* __restrict__ rank,
                                              int* __restrict__ col) {
  int e = blockIdx.x * 256 + threadIdx.x;
  if (e < NE) {
    int d = dst[e];
    col[row_start[d] + rank[e]] = src[e];
  }
}

// ---------------- weight prep: Wt[mat] = split(W^T) as bf16 hi/lo [n][k] ----------------
__global__ __launch_bounds__(256) void k_prep(const float* __restrict__ Wg,
                                              const float* __restrict__ Wo1,
                                              unsigned short* __restrict__ wt) {
  int idx = blockIdx.x * 256 + threadIdx.x;  // 4 * 16384
  int mat = idx >> 14, rem = idx & 16383;
  int k = rem >> 7, n = rem & 127;
  const float* Wsrc = (mat < 3) ? (Wg + mat * 16384) : Wo1;
  float v = Wsrc[k * 128 + n];
  unsigned short hi = f2bf(v);
  float lo = v - bf2f(hi);
  unsigned short* base = wt + mat * 32768;
  base[n * 128 + k] = hi;
  base[16384 + n * 128 + k] = f2bf(lo);
}

// ---------------- embedding: xs = (nf @ W_emb + b_emb) * nsrc ----------------
__global__ __launch_bounds__(256) void k_embed(const float* __restrict__ nf,
                                               const float* __restrict__ W,
                                               const float* __restrict__ b,
                                               const float* __restrict__ nsrc,
                                               float* __restrict__ xs) {
  int idx = blockIdx.x * 256 + threadIdx.x;
  int n = idx >> 7, j = idx & 127;
  const float* f = nf + n * 4;
  float acc = b[j];
  acc += f[0] * W[j] + f[1] * W[128 + j] + f[2] * W[256 + j] + f[3] * W[384 + j];
  xs[idx] = acc * nsrc[n];
}

// ---------------- SpMM: a[n] = ndst[n]*sum xs[src]; write bf16 hi/lo split ----------------
// masked 4-deep ILP: always 4 row-loads in flight, tails handled by 0/1 FMA masks
__global__ __launch_bounds__(256) void k_spmm(const float* __restrict__ xs,
                                              unsigned short* __restrict__ ahi,
                                              unsigned short* __restrict__ alo,
                                              const int* __restrict__ col,
                                              const int* __restrict__ row_start,
                                              const int* __restrict__ in_cnt,
                                              const float* __restrict__ ndst) {
  int node = blockIdx.x * 4 + (threadIdx.x >> 6);
  int lane = threadIdx.x & 63;
  int half = lane >> 5;
  int ql = lane & 31;
  int start = row_start[node];
  int cnt = in_cnt[node];
  float4 acc = make_float4(0.f, 0.f, 0.f, 0.f);
  const float4* X4 = (const float4*)xs;
  for (int base = 0; base < cnt; base += 64) {
    int m = min(cnt - base, 64);
    int ccol = (lane < m) ? col[start + base + lane] : 0;
    for (int jj = 0; jj < m; jj += 8) {
      int i0 = jj + half, i1 = i0 + 2, i2 = i0 + 4, i3 = i0 + 6;
      int mm = m - 1;
      int s0 = __shfl(ccol, min(i0, mm));
      int s1 = __shfl(ccol, min(i1, mm));
      int s2 = __shfl(ccol, min(i2, mm));
      int s3 = __shfl(ccol, min(i3, mm));
      float f0 = (i0 < m) ? 1.f : 0.f;
      float f1 = (i1 < m) ? 1.f : 0.f;
      float f2 = (i2 < m) ? 1.f : 0.f;
      float f3 = (i3 < m) ? 1.f : 0.f;
      float4 v0 = X4[(size_t)s0 * 32 + ql];
      float4 v1 = X4[(size_t)s1 * 32 + ql];
      float4 v2 = X4[(size_t)s2 * 32 + ql];
      float4 v3 = X4[(size_t)s3 * 32 + ql];
      acc.x = fmaf(f0, v0.x, acc.x); acc.y = fmaf(f0, v0.y, acc.y);
      acc.z = fmaf(f0, v0.z, acc.z); acc.w = fmaf(f0, v0.w, acc.w);
      acc.x = fmaf(f1, v1.x, acc.x); acc.y = fmaf(f1, v1.y, acc.y);
      acc.z = fmaf(f1, v1.z, acc.z); acc.w = fmaf(f1, v1.w, acc.w);
      acc.x = fmaf(f2, v2.x, acc.x); acc.y = fmaf(f2, v2.y, acc.y);
      acc.z = fmaf(f2, v2.z, acc.z); acc.w = fmaf(f2, v2.w, acc.w);
      acc.x = fmaf(f3, v3.x, acc.x); acc.y = fmaf(f3, v3.y, acc.y);
      acc.z = fmaf(f3, v3.z, acc.z); acc.w = fmaf(f3, v3.w, acc.w);
    }
  }
  acc.x += __shfl_down(acc.x, 32);
  acc.y += __shfl_down(acc.y, 32);
  acc.z += __shfl_down(acc.z, 32);
  acc.w += __shfl_down(acc.w, 32);
  if (half == 0) {
    float nd = ndst[node];
    float v0 = acc.x * nd, v1 = acc.y * nd, v2 = acc.z * nd, v3 = acc.w * nd;
    ushort4 h, l;
    h.x = f2bf(v0); l.x = f2bf(v0 - bf2f(h.x));
    h.y = f2bf(v1); l.y = f2bf(v1 - bf2f(h.y));
    h.z = f2bf(v2); l.z = f2bf(v2 - bf2f(h.z));
    h.w = f2bf(v3); l.w = f2bf(v3 - bf2f(h.w));
    *(ushort4*)(ahi + (size_t)node * 128 + ql * 4) = h;
    *(ushort4*)(alo + (size_t)node * 128 + ql * 4) = l;
  }
}

// ---------------- MFMA GEMM (bf16x3 split): out = relu(A @ Wt^T + bias) ----------------
// modes: 0 = write fp32 * nsrc (xs), 1 = write bf16 hi/lo, 3 = fused final dot with W_o2
__global__ __launch_bounds__(256) void k_gemm_mfma(
    const unsigned short* __restrict__ Ahi, const unsigned short* __restrict__ Alo,
    const unsigned short* __restrict__ Wth, const unsigned short* __restrict__ Wtl,
    const float* __restrict__ bias, float* __restrict__ outf,
    unsigned short* __restrict__ outhi, unsigned short* __restrict__ outlo,
    const float* __restrict__ nsrc, const float* __restrict__ W_o2,
    const float* __restrict__ b_o2, int M, int mode) {
  __shared__ unsigned short sm[2 * 64 * 128];  // Ah (16KB) then Al (16KB)
  __shared__ float smred[4][64];
  int tid = threadIdx.x;
  int lane = tid & 63, w = tid >> 6;
  int tile0 = blockIdx.x * 64;

  // stage A hi/lo via global_load_lds: linear LDS dest, pre-XOR-swizzled global src
  {
    int slot = lane & 15;
#pragma unroll
    for (int j = 0; j < 4; ++j) {
      int ldsoff = w * 4096 + j * 1024;       // byte offset within half
      int row = (ldsoff >> 8) + (lane >> 4);  // 0..63
      int grow = tile0 + row;
      if (grow > M - 1) grow = M - 1;
      size_t gsrc = (size_t)grow * 256 + (size_t)(((slot ^ (row & 7)) << 4));
      gload16((const char*)Ahi + gsrc, (char*)sm + ldsoff);
      gload16((const char*)Alo + gsrc, (char*)sm + 16384 + ldsoff);
    }
  }

  // B fragments in registers (Wt layout [n][k] bf16)
  bf16x8 bh[2][4], bl[2][4];
  {
    int koff = (lane >> 4) * 8;
#pragma unroll
    for (int cf = 0; cf < 2; ++cf) {
      int n = w * 32 + cf * 16 + (lane & 15);
      const unsigned short* ph = Wth + (size_t)n * 128 + koff;
      const unsigned short* pl = Wtl + (size_t)n * 128 + koff;
#pragma unroll
      for (int kc = 0; kc < 4; ++kc) {
        bh[cf][kc] = *(const bf16x8*)(ph + kc * 32);
        bl[cf][kc] = *(const bf16x8*)(pl + kc * 32);
      }
    }
  }

  f32x4 acc[4][2] = {};
  __syncthreads();  // drains vmcnt -> staged A complete

  int r15 = lane & 15, kq = lane >> 4;
  for (int kc = 0; kc < 4; ++kc) {
    bf16x8 ah[4], al[4];
#pragma unroll
    for (int m = 0; m < 4; ++m) {
      int row = m * 16 + r15;
      int boff = row * 256 + ((((kc * 4 + kq) ^ (row & 7))) << 4);
      ah[m] = *(const bf16x8*)((const char*)sm + boff);
      al[m] = *(const bf16x8*)((const char*)sm + 16384 + boff);
    }
#pragma unroll
    for (int m = 0; m < 4; ++m)
#pragma unroll
      for (int cf = 0; cf < 2; ++cf) {
        acc[m][cf] = __builtin_amdgcn_mfma_f32_16x16x32_bf16(ah[m], bh[cf][kc], acc[m][cf], 0, 0, 0);
        acc[m][cf] = __builtin_amdgcn_mfma_f32_16x16x32_bf16(ah[m], bl[cf][kc], acc[m][cf], 0, 0, 0);
        acc[m][cf] = __builtin_amdgcn_mfma_f32_16x16x32_bf16(al[m], bh[cf][kc], acc[m][cf], 0, 0, 0);
      }
  }

  // D[row=(kq*4+i)+m*16][col=r15+cf*16+w*32]
  if (mode == 3) {
    float w2v[2], bv2[2];
#pragma unroll
    for (int cf = 0; cf < 2; ++cf) {
      int colg = w * 32 + cf * 16 + r15;
      w2v[cf] = W_o2[colg];
      bv2[cf] = bias[colg];
    }
#pragma unroll
    for (int m = 0; m < 4; ++m) {
#pragma unroll
      for (int i = 0; i < 4; ++i) {
        float p = fmaxf(acc[m][0][i] + bv2[0], 0.f) * w2v[0] +
                  fmaxf(acc[m][1][i] + bv2[1], 0.f) * w2v[1];
#pragma unroll
        for (int msk = 1; msk < 16; msk <<= 1) p += __shfl_xor(p, msk);
        if (r15 == 0) smred[w][m * 16 + kq * 4 + i] = p;
      }
    }
    __syncthreads();
    if (tid < 64) {
      int gr = tile0 + tid;
      if (gr < M)
        outf[gr] = smred[0][tid] + smred[1][tid] + smred[2][tid] + smred[3][tid] + b_o2[0];
    }
    return;
  }
#pragma unroll
  for (int cf = 0; cf < 2; ++cf) {
    int colg = w * 32 + cf * 16 + r15;
    float bv = bias[colg];
#pragma unroll
    for (int m = 0; m < 4; ++m) {
#pragma unroll
      for (int i = 0; i < 4; ++i) {
        int gr = tile0 + m * 16 + kq * 4 + i;
        if (gr < M) {
          float v = fmaxf(acc[m][cf][i] + bv, 0.f);
          if (mode == 0) {
            outf[(size_t)gr * 128 + colg] = v * nsrc[gr];
          } else {
            unsigned short h = f2bf(v);
            outhi[(size_t)gr * 128 + colg] = h;
            outlo[(size_t)gr * 128 + colg] = f2bf(v - bf2f(h));
          }
        }
      }
    }
  }
}

extern "C" void kernel_launch(void* const* d_in, const int* in_sizes, int n_in,
                              void* d_out, int out_size, void* d_ws, size_t ws_size,
                              hipStream_t stream) {
  const float* node_feats = (const float*)d_in[0];
  const int* src = (const int*)d_in[1];
  const int* dst = (const int*)d_in[2];
  const float* W_emb = (const float*)d_in[3];
  const float* b_emb = (const float*)d_in[4];
  const float* W_g = (const float*)d_in[5];
  const float* b_g = (const float*)d_in[6];
  const float* W_o1 = (const float*)d_in[7];
  const float* b_o1 = (const float*)d_in[8];
  const float* W_o2 = (const float*)d_in[9];
  const float* b_o2 = (const float*)d_in[10];
  float* out = (float*)d_out;

  char* ws = (char*)d_ws;
  int* out_cnt   = (int*)(ws + 0);
  int* in_cnt    = (int*)(ws + 200704);
  int* row_start = (int*)(ws + 401408);
  float* nsrc    = (float*)(ws + 602112);
  float* ndst    = (float*)(ws + 802816);
  int* bsum      = (int*)(ws + 1003520);
  int* boff      = (int*)(ws + 1004544);
  int* col       = (int*)(ws + 1005568);                  // 2,560,000 B
  unsigned short* wt = (unsigned short*)(ws + 3565568);   // 262,144 B
  float* X       = (float*)(ws + 3827712);                // 25.6 MB
  unsigned short* Xu = (unsigned short*)(ws + 3827712);
  int* rank      = (int*)(ws + 3827712);                  // aliases X (dead before embed)
  unsigned short* Ahi = (unsigned short*)(ws + 29427712); // 12.8 MB
  unsigned short* Alo = (unsigned short*)(ws + 42227712); // 12.8 MB

  hipMemsetAsync(d_ws, 0, 401408, stream);  // out_cnt, in_cnt

  k_deg<<<(NE + 255) / 256, 256, 0, stream>>>(src, dst, out_cnt, in_cnt, rank);
  k_scan1<<<SCAN_B, 256, 0, stream>>>(out_cnt, in_cnt, nsrc, ndst, bsum);
  k_scan2<<<1, 256, 0, stream>>>(bsum, boff);
  k_scan3<<<SCAN_B, 256, 0, stream>>>(in_cnt, boff, row_start);
  k_fill<<<(NE + 255) / 256, 256, 0, stream>>>(src, dst, row_start, rank, col);
  k_prep<<<256, 256, 0, stream>>>(W_g, W_o1, wt);
  k_embed<<<(NN * 128) / 256, 256, 0, stream>>>(node_feats, W_emb, b_emb, nsrc, X);

  int gemm_grid = (NN + 63) / 64;
  for (int l = 0; l < 3; ++l) {
    k_spmm<<<NN / 4, 256, 0, stream>>>(X, Ahi, Alo, col, row_start, in_cnt, ndst);
    unsigned short* wth = wt + l * 32768;
    unsigned short* wtl = wth + 16384;
    if (l < 2) {
      k_gemm_mfma<<<gemm_grid, 256, 0, stream>>>(Ahi, Alo, wth, wtl, b_g + l * 128,
                                                 X, nullptr, nullptr, nsrc,
                                                 nullptr, nullptr, NN, 0);
    } else {
      k_gemm_mfma<<<gemm_grid, 256, 0, stream>>>(Ahi, Alo, wth, wtl, b_g + l * 128,
                                                 nullptr, Xu, Xu + 6400000, nsrc,
                                                 nullptr, nullptr, NN, 1);
    }
  }
  // o1 GEMM with fused final dot (reads hi/lo from X region, writes out directly)
  k_gemm_mfma<<<gemm_grid, 256, 0, stream>>>(Xu, Xu + 6400000, wt + 3 * 32768,
                                             wt + 3 * 32768 + 16384, b_o1,
                                             out, nullptr, nullptr, nsrc,
                                             W_o2, b_o2, NN, 3);
}